// Round 1
// baseline (1194.643 us; speedup 1.0000x reference)
//
#include <hip/hip_runtime.h>
#include <math.h>

#define N_NODES 50000
#define N_EDGES 800000
#define DIM 256
#define N_GRAPHS 128

// ---------------- degree + counts ----------------
__global__ __launch_bounds__(256) void deg_count_kernel(
    const int* __restrict__ dst, const float* __restrict__ ew,
    float* __restrict__ deg, int* __restrict__ counts) {
  int e = blockIdx.x * 256 + threadIdx.x;
  if (e < N_EDGES) {
    int d = dst[e];
    atomicAdd(&deg[d], ew[e]);
    atomicAdd(&counts[d], 1);
  }
}

__global__ __launch_bounds__(256) void dinv_kernel(
    const float* __restrict__ deg, float* __restrict__ dinv) {
  int n = blockIdx.x * 256 + threadIdx.x;
  if (n < N_NODES) {
    float d = deg[n] + 1.0f;           // self-loop weight 1
    dinv[n] = 1.0f / sqrtf(d);         // d >= 1 always
  }
}

// ---------------- exclusive scan (3 phases), chunk = 1024 ----------------
#define SCAN_CHUNK 1024
#define SCAN_BLOCKS ((N_NODES + SCAN_CHUNK - 1) / SCAN_CHUNK)

__global__ __launch_bounds__(256) void scan_phaseA(
    const int* __restrict__ counts, int* __restrict__ blockSums) {
  __shared__ int sdata[256];
  int b = blockIdx.x, t = threadIdx.x;
  int base = b * SCAN_CHUNK + t * 4;
  int s = 0;
#pragma unroll
  for (int i = 0; i < 4; ++i) {
    int idx = base + i;
    if (idx < N_NODES) s += counts[idx];
  }
  sdata[t] = s;
  __syncthreads();
  for (int off = 128; off > 0; off >>= 1) {
    if (t < off) sdata[t] += sdata[t + off];
    __syncthreads();
  }
  if (t == 0) blockSums[b] = sdata[0];
}

__global__ void scan_phaseB(int* __restrict__ blockSums, int* __restrict__ rs) {
  if (threadIdx.x == 0 && blockIdx.x == 0) {
    int acc = 0;
    for (int i = 0; i < SCAN_BLOCKS; ++i) {
      int v = blockSums[i];
      blockSums[i] = acc;
      acc += v;
    }
    rs[N_NODES] = acc;
  }
}

__global__ __launch_bounds__(256) void scan_phaseC(
    const int* __restrict__ counts, const int* __restrict__ blockSums,
    int* __restrict__ rs, int* __restrict__ cursor) {
  __shared__ int sdata[256];
  int b = blockIdx.x, t = threadIdx.x;
  int base = b * SCAN_CHUNK + t * 4;
  int v[4];
  int s = 0;
#pragma unroll
  for (int i = 0; i < 4; ++i) {
    int idx = base + i;
    v[i] = (idx < N_NODES) ? counts[idx] : 0;
    s += v[i];
  }
  sdata[t] = s;
  __syncthreads();
  // inclusive Hillis-Steele scan over 256 thread sums
  for (int off = 1; off < 256; off <<= 1) {
    int x = (t >= off) ? sdata[t - off] : 0;
    __syncthreads();
    sdata[t] += x;
    __syncthreads();
  }
  int excl = (t == 0) ? 0 : sdata[t - 1];
  int o = blockSums[b] + excl;
#pragma unroll
  for (int i = 0; i < 4; ++i) {
    int idx = base + i;
    if (idx < N_NODES) { rs[idx] = o; cursor[idx] = o; }
    o += v[i];
  }
}

// ---------------- CSR fill (norm precomputed, layer-independent) ----------------
__global__ __launch_bounds__(256) void fill_kernel(
    const int* __restrict__ src, const int* __restrict__ dst,
    const float* __restrict__ ew, const float* __restrict__ dinv,
    int* __restrict__ cursor, int* __restrict__ csrc, float* __restrict__ cw) {
  int e = blockIdx.x * 256 + threadIdx.x;
  if (e < N_EDGES) {
    int s = src[e], d = dst[e];
    float norm = dinv[s] * ew[e] * dinv[d];
    int p = atomicAdd(&cursor[d], 1);
    csrc[p] = s;
    cw[p] = norm;
  }
}

// ---------------- f32 tiled GEMM: C[M,256] = A[M,256] @ B[256,256] ----------------
__global__ __launch_bounds__(256) void gemm_f32(
    const float* __restrict__ A, const float* __restrict__ B,
    float* __restrict__ C, int M) {
  __shared__ float As[16][65];
  __shared__ float Bs[16][65];
  int tid = threadIdx.x;
  int bm = blockIdx.x * 64;
  int bn = blockIdx.y * 64;
  int tx = tid & 15, ty = tid >> 4;
  float acc[4][4] = {};
  for (int k0 = 0; k0 < 256; k0 += 16) {
    {
      int r = bm + (tid >> 2);
      int c = k0 + (tid & 3) * 4;
      float4 v = make_float4(0.f, 0.f, 0.f, 0.f);
      if (r < M) v = *(const float4*)(A + (size_t)r * DIM + c);
      int kk = (tid & 3) * 4, m = tid >> 2;
      As[kk + 0][m] = v.x;
      As[kk + 1][m] = v.y;
      As[kk + 2][m] = v.z;
      As[kk + 3][m] = v.w;
    }
    {
      int k = tid >> 4;
      int n = (tid & 15) * 4;
      float4 v = *(const float4*)(B + (size_t)(k0 + k) * DIM + bn + n);
      Bs[k][n + 0] = v.x;
      Bs[k][n + 1] = v.y;
      Bs[k][n + 2] = v.z;
      Bs[k][n + 3] = v.w;
    }
    __syncthreads();
#pragma unroll
    for (int k = 0; k < 16; ++k) {
      float a[4], b[4];
#pragma unroll
      for (int i = 0; i < 4; ++i) a[i] = As[k][ty * 4 + i];
#pragma unroll
      for (int j = 0; j < 4; ++j) b[j] = Bs[k][tx * 4 + j];
#pragma unroll
      for (int i = 0; i < 4; ++i)
#pragma unroll
        for (int j = 0; j < 4; ++j) acc[i][j] += a[i] * b[j];
    }
    __syncthreads();
  }
#pragma unroll
  for (int i = 0; i < 4; ++i) {
    int r = bm + ty * 4 + i;
    if (r < M) {
#pragma unroll
      for (int j = 0; j < 4; ++j)
        C[(size_t)r * DIM + bn + tx * 4 + j] = acc[i][j];
    }
  }
}

// ---------------- SpMM via CSR: one block per node; fuses self-loop+bias+relu ----
__global__ __launch_bounds__(256) void spmm_csr(
    const float* __restrict__ xw, const int* __restrict__ rs,
    const int* __restrict__ csrc, const float* __restrict__ cw,
    const float* __restrict__ dinv, const float* __restrict__ bias,
    float* __restrict__ xout) {
  int n = blockIdx.x;
  int d = threadIdx.x;
  float di = dinv[n];
  float acc = xw[(size_t)n * DIM + d] * (di * di);
  int s = rs[n], e = rs[n + 1];
  for (int i = s; i < e; ++i) {
    acc += xw[(size_t)csrc[i] * DIM + d] * cw[i];
  }
  xout[(size_t)n * DIM + d] = fmaxf(acc + bias[d], 0.0f);
}

// ---------------- pooling: one block per graph (batch sorted) ----------------
__device__ __forceinline__ int lower_bound_dev(const int* a, int n, int key) {
  int lo = 0, hi = n;
  while (lo < hi) {
    int mid = (lo + hi) >> 1;
    if (a[mid] < key) lo = mid + 1; else hi = mid;
  }
  return lo;
}

__global__ __launch_bounds__(256) void pool_kernel(
    const float* __restrict__ x, const int* __restrict__ batch,
    float* __restrict__ h) {
  int g = blockIdx.x;
  int d = threadIdx.x;
  int start = lower_bound_dev(batch, N_NODES, g);
  int end = lower_bound_dev(batch, N_NODES, g + 1);
  float sum = 0.f, mx = 0.f;  // relu output >= 0; empty segment -> 0 (matches ref)
  for (int i = start; i < end; ++i) {
    float v = x[(size_t)i * DIM + d];
    sum += v;
    mx = fmaxf(mx, v);
  }
  float cnt = (float)(end - start);
  h[(size_t)g * (2 * DIM) + d] = sum / fmaxf(cnt, 1.0f);
  h[(size_t)g * (2 * DIM) + DIM + d] = mx;
}

// ---------------- FC head: one block per graph ----------------
__global__ __launch_bounds__(256) void fc_kernel(
    const float* __restrict__ h, const float* __restrict__ fc1_w,
    const float* __restrict__ fc1_b, const float* __restrict__ fc2_w,
    const float* __restrict__ fc2_b, float* __restrict__ out) {
  int g = blockIdx.x;
  int j = threadIdx.x;
  __shared__ float hs[2 * DIM];
  __shared__ float s0[256], s1[256];
  hs[j] = h[(size_t)g * (2 * DIM) + j];
  hs[j + 256] = h[(size_t)g * (2 * DIM) + 256 + j];
  __syncthreads();
  float acc = fc1_b[j];
  for (int k = 0; k < 2 * DIM; ++k) acc += hs[k] * fc1_w[(size_t)k * DIM + j];
  float r = fmaxf(acc, 0.0f);
  s0[j] = r * fc2_w[j * 2 + 0];
  s1[j] = r * fc2_w[j * 2 + 1];
  __syncthreads();
  for (int off = 128; off > 0; off >>= 1) {
    if (j < off) { s0[j] += s0[j + off]; s1[j] += s1[j + off]; }
    __syncthreads();
  }
  if (j == 0) {
    out[g * 2 + 0] = s0[0] + fc2_b[0];
    out[g * 2 + 1] = s1[0] + fc2_b[1];
  }
}

extern "C" void kernel_launch(void* const* d_in, const int* in_sizes, int n_in,
                              void* d_out, int out_size, void* d_ws, size_t ws_size,
                              hipStream_t stream) {
  const float* emb_x = (const float*)d_in[0];
  const int* eidx = (const int*)d_in[1];
  const int* esrc = eidx;
  const int* edst = eidx + N_EDGES;
  const float* ew = (const float*)d_in[2];
  const int* batch = (const int*)d_in[3];
  const float* W1 = (const float*)d_in[4];
  const float* b1 = (const float*)d_in[5];
  const float* W2 = (const float*)d_in[6];
  const float* b2 = (const float*)d_in[7];
  const float* W3 = (const float*)d_in[8];
  const float* b3 = (const float*)d_in[9];
  const float* fc1_w = (const float*)d_in[10];
  const float* fc1_b = (const float*)d_in[11];
  const float* fc2_w = (const float*)d_in[12];
  const float* fc2_b = (const float*)d_in[13];
  float* out = (float*)d_out;

  char* ws = (char*)d_ws;
  size_t off = 0;
  auto take = [&](size_t bytes) -> char* {
    char* p = ws + off;
    off = (off + bytes + 255) & ~(size_t)255;
    return p;
  };
  float* XW = (float*)take((size_t)N_NODES * DIM * 4);
  float* X = (float*)take((size_t)N_NODES * DIM * 4);
  float* deg = (float*)take(N_NODES * 4);
  float* dinv = (float*)take(N_NODES * 4);
  int* counts = (int*)take(N_NODES * 4);
  int* rs = (int*)take((N_NODES + 1) * 4);
  int* cursor = (int*)take(N_NODES * 4);
  int* blockSums = (int*)take(64 * 4);
  int* csrc = (int*)take(N_EDGES * 4);
  float* cw = (float*)take(N_EDGES * 4);
  float* h = (float*)take((size_t)N_GRAPHS * 2 * DIM * 4);

  hipMemsetAsync(deg, 0, N_NODES * 4, stream);
  hipMemsetAsync(counts, 0, N_NODES * 4, stream);

  int eblocks = (N_EDGES + 255) / 256;
  int nblocks = (N_NODES + 255) / 256;

  deg_count_kernel<<<eblocks, 256, 0, stream>>>(edst, ew, deg, counts);
  dinv_kernel<<<nblocks, 256, 0, stream>>>(deg, dinv);
  scan_phaseA<<<SCAN_BLOCKS, 256, 0, stream>>>(counts, blockSums);
  scan_phaseB<<<1, 64, 0, stream>>>(blockSums, rs);
  scan_phaseC<<<SCAN_BLOCKS, 256, 0, stream>>>(counts, blockSums, rs, cursor);
  fill_kernel<<<eblocks, 256, 0, stream>>>(esrc, edst, ew, dinv, cursor, csrc, cw);

  dim3 ggrid((N_NODES + 63) / 64, DIM / 64);

  // layer 1
  gemm_f32<<<ggrid, 256, 0, stream>>>(emb_x, W1, XW, N_NODES);
  spmm_csr<<<N_NODES, 256, 0, stream>>>(XW, rs, csrc, cw, dinv, b1, X);
  // layer 2
  gemm_f32<<<ggrid, 256, 0, stream>>>(X, W2, XW, N_NODES);
  spmm_csr<<<N_NODES, 256, 0, stream>>>(XW, rs, csrc, cw, dinv, b2, X);
  // layer 3
  gemm_f32<<<ggrid, 256, 0, stream>>>(X, W3, XW, N_NODES);
  spmm_csr<<<N_NODES, 256, 0, stream>>>(XW, rs, csrc, cw, dinv, b3, X);

  pool_kernel<<<N_GRAPHS, 256, 0, stream>>>(X, batch, h);
  fc_kernel<<<N_GRAPHS, 256, 0, stream>>>(h, fc1_w, fc1_b, fc2_w, fc2_b, out);
}

// Round 2
// 788.675 us; speedup vs baseline: 1.5147x; 1.5147x over previous
//
#include <hip/hip_runtime.h>
#include <math.h>

#define N_NODES 50000
#define N_PAD 50048          // padded rows for MFMA staging (multiple of 128 above 50000)
#define N_EDGES 800000
#define DIM 256
#define N_GRAPHS 128

using f32x4 = __attribute__((ext_vector_type(4))) float;
using s16x8 = __attribute__((ext_vector_type(8))) short;

// ---------------- degree + counts ----------------
__global__ __launch_bounds__(256) void deg_count_kernel(
    const int* __restrict__ dst, const float* __restrict__ ew,
    float* __restrict__ deg, int* __restrict__ counts) {
  int e = blockIdx.x * 256 + threadIdx.x;
  if (e < N_EDGES) {
    int d = dst[e];
    atomicAdd(&deg[d], ew[e]);
    atomicAdd(&counts[d], 1);
  }
}

__global__ __launch_bounds__(256) void dinv_kernel(
    const float* __restrict__ deg, float* __restrict__ dinv) {
  int n = blockIdx.x * 256 + threadIdx.x;
  if (n < N_NODES) {
    float d = deg[n] + 1.0f;
    dinv[n] = 1.0f / sqrtf(d);
  }
}

// ---------------- exclusive scan (3 phases) ----------------
#define SCAN_CHUNK 1024
#define SCAN_BLOCKS ((N_NODES + SCAN_CHUNK - 1) / SCAN_CHUNK)

__global__ __launch_bounds__(256) void scan_phaseA(
    const int* __restrict__ counts, int* __restrict__ blockSums) {
  __shared__ int sdata[256];
  int b = blockIdx.x, t = threadIdx.x;
  int base = b * SCAN_CHUNK + t * 4;
  int s = 0;
#pragma unroll
  for (int i = 0; i < 4; ++i) {
    int idx = base + i;
    if (idx < N_NODES) s += counts[idx];
  }
  sdata[t] = s;
  __syncthreads();
  for (int off = 128; off > 0; off >>= 1) {
    if (t < off) sdata[t] += sdata[t + off];
    __syncthreads();
  }
  if (t == 0) blockSums[b] = sdata[0];
}

__global__ void scan_phaseB(int* __restrict__ blockSums, int* __restrict__ rs) {
  if (threadIdx.x == 0 && blockIdx.x == 0) {
    int acc = 0;
    for (int i = 0; i < SCAN_BLOCKS; ++i) {
      int v = blockSums[i];
      blockSums[i] = acc;
      acc += v;
    }
    rs[N_NODES] = acc;
  }
}

__global__ __launch_bounds__(256) void scan_phaseC(
    const int* __restrict__ counts, const int* __restrict__ blockSums,
    int* __restrict__ rs, int* __restrict__ cursor) {
  __shared__ int sdata[256];
  int b = blockIdx.x, t = threadIdx.x;
  int base = b * SCAN_CHUNK + t * 4;
  int v[4];
  int s = 0;
#pragma unroll
  for (int i = 0; i < 4; ++i) {
    int idx = base + i;
    v[i] = (idx < N_NODES) ? counts[idx] : 0;
    s += v[i];
  }
  sdata[t] = s;
  __syncthreads();
  for (int off = 1; off < 256; off <<= 1) {
    int x = (t >= off) ? sdata[t - off] : 0;
    __syncthreads();
    sdata[t] += x;
    __syncthreads();
  }
  int excl = (t == 0) ? 0 : sdata[t - 1];
  int o = blockSums[b] + excl;
#pragma unroll
  for (int i = 0; i < 4; ++i) {
    int idx = base + i;
    if (idx < N_NODES) { rs[idx] = o; cursor[idx] = o; }
    o += v[i];
  }
}

// ---------------- CSR fill ----------------
__global__ __launch_bounds__(256) void fill_kernel(
    const int* __restrict__ src, const int* __restrict__ dst,
    const float* __restrict__ ew, const float* __restrict__ dinv,
    int* __restrict__ cursor, int* __restrict__ csrc, float* __restrict__ cw) {
  int e = blockIdx.x * 256 + threadIdx.x;
  if (e < N_EDGES) {
    int s = src[e], d = dst[e];
    float norm = dinv[s] * ew[e] * dinv[d];
    int p = atomicAdd(&cursor[d], 1);
    csrc[p] = s;
    cw[p] = norm;
  }
}

// ---------------- f32 -> bf16 hi/lo split helpers ----------------
__device__ __forceinline__ void bf16_split(float f, ushort& hh, ushort& ll) {
  unsigned u = __float_as_uint(f);
  unsigned r = u + 0x7FFFu + ((u >> 16) & 1u);
  hh = (ushort)(r >> 16);
  float hf = __uint_as_float(((unsigned)hh) << 16);
  float d = f - hf;
  unsigned u2 = __float_as_uint(d);
  unsigned r2 = u2 + 0x7FFFu + ((u2 >> 16) & 1u);
  ll = (ushort)(r2 >> 16);
}

// split emb_x into hi/lo bf16 buffers (4 floats/thread)
__global__ __launch_bounds__(256) void split_x_kernel(
    const float* __restrict__ x, ushort* __restrict__ hi, ushort* __restrict__ lo,
    int n4) {
  int i = blockIdx.x * 256 + threadIdx.x;
  if (i >= n4) return;
  float4 v = ((const float4*)x)[i];
  ushort4 h, l;
  bf16_split(v.x, h.x, l.x);
  bf16_split(v.y, h.y, l.y);
  bf16_split(v.z, h.z, l.z);
  bf16_split(v.w, h.w, l.w);
  ((ushort4*)hi)[i] = h;
  ((ushort4*)lo)[i] = l;
}

// transpose + split weights: W [K=256][N=256] f32 -> Wt_hi/Wt_lo [N][K] bf16
__global__ __launch_bounds__(256) void prep_w_kernel(
    const float* __restrict__ W1, const float* __restrict__ W2, const float* __restrict__ W3,
    ushort* __restrict__ wt) {  // wt: 6 planes of 256*256: [W1h,W1l,W2h,W2l,W3h,W3l]
  int k = blockIdx.x;            // 0..255
  int w = blockIdx.y;            // 0..2
  int n = threadIdx.x;           // 0..255
  const float* W = (w == 0) ? W1 : (w == 1) ? W2 : W3;
  float v = W[k * 256 + n];
  ushort h, l;
  bf16_split(v, h, l);
  ushort* hplane = wt + (size_t)w * 2 * 256 * 256;
  ushort* lplane = hplane + 256 * 256;
  hplane[n * 256 + k] = h;
  lplane[n * 256 + k] = l;
}

// ---------------- split-bf16 MFMA GEMM ----------------
// C[M,256] (f32) = (Ahi+Alo)[M,256] @ W[256,256], computed as
// Ahi*Wh + Alo*Wh + Ahi*Wl over effective K=768.
// Wt buffers are [N][K] bf16 (pre-transposed).
#define BM 128
#define BN 128
#define BK 32

__device__ __forceinline__ void gload16(const void* g, void* l) {
  __builtin_amdgcn_global_load_lds(
      (const __attribute__((address_space(1))) void*)g,
      (__attribute__((address_space(3))) void*)l, 16, 0, 0);
}

__global__ __launch_bounds__(256) void gemm_mfma(
    const ushort* __restrict__ Ahi, const ushort* __restrict__ Alo,  // [N_PAD][256]
    const ushort* __restrict__ Wth, const ushort* __restrict__ Wtl,  // [256][256] n-major
    float* __restrict__ C, int M) {
  __shared__ ushort Asl[BM * BK];  // [128][32]
  __shared__ ushort Bsl[BN * BK];
  int tid = threadIdx.x;
  int bm = blockIdx.x * BM;
  int bn = blockIdx.y * BN;
  int wave = tid >> 6, lane = tid & 63;
  int wr = (wave >> 1) * 64;
  int wc = (wave & 1) * 64;
  int l15 = lane & 15;
  int lk = (lane >> 4) * 8;

  f32x4 acc[4][4];
#pragma unroll
  for (int i = 0; i < 4; ++i)
#pragma unroll
    for (int j = 0; j < 4; ++j) acc[i][j] = (f32x4){0.f, 0.f, 0.f, 0.f};

  int srow = tid >> 2;        // chunk row for it=0 (0..63)
  int sslot = tid & 3;        // 16B slot within 64B row

  for (int s = 0; s < 24; ++s) {
    int pass = s >> 3;
    int k0 = (s & 7) * BK;
    const ushort* As = (pass == 1) ? Alo : Ahi;
    const ushort* Bs = (pass == 2) ? Wtl : Wth;
#pragma unroll
    for (int it = 0; it < 2; ++it) {
      int row = it * 64 + srow;
      const ushort* ga = As + (size_t)(bm + row) * 256 + k0 + sslot * 8;
      gload16(ga, Asl + (row * 32 + sslot * 8));
      const ushort* gb = Bs + (size_t)(bn + row) * 256 + k0 + sslot * 8;
      gload16(gb, Bsl + (row * 32 + sslot * 8));
    }
    __syncthreads();
    s16x8 af[4], bf[4];
#pragma unroll
    for (int f = 0; f < 4; ++f) {
      af[f] = *(const s16x8*)(Asl + (wr + f * 16 + l15) * 32 + lk);
      bf[f] = *(const s16x8*)(Bsl + (wc + f * 16 + l15) * 32 + lk);
    }
#pragma unroll
    for (int i = 0; i < 4; ++i)
#pragma unroll
      for (int j = 0; j < 4; ++j)
        acc[i][j] = __builtin_amdgcn_mfma_f32_16x16x32_bf16(af[i], bf[j], acc[i][j], 0, 0, 0);
    __syncthreads();
  }

#pragma unroll
  for (int i = 0; i < 4; ++i) {
    int rbase = bm + wr + i * 16 + (lane >> 4) * 4;
#pragma unroll
    for (int j = 0; j < 4; ++j) {
      int col = bn + wc + j * 16 + l15;
#pragma unroll
      for (int r = 0; r < 4; ++r) {
        int row = rbase + r;
        if (row < M) C[(size_t)row * 256 + col] = acc[i][j][r];
      }
    }
  }
}

// ---------------- SpMM: 1 wave per node, float4 lanes, 4-edge unroll ----------------
// MODE 0: write bf16 hi/lo (feeds next layer's MFMA GEMM)
// MODE 1: write f32 (feeds pooling)
template <int MODE>
__global__ __launch_bounds__(256) void spmm4(
    const float* __restrict__ xw, const int* __restrict__ rs,
    const int* __restrict__ csrc, const float* __restrict__ cw,
    const float* __restrict__ dinv, const float* __restrict__ bias,
    float* __restrict__ xf32, ushort* __restrict__ xhi, ushort* __restrict__ xlo) {
  int wave = threadIdx.x >> 6, lane = threadIdx.x & 63;
  int n = blockIdx.x * 4 + wave;  // 50000 = 12500*4 exact
  float di = dinv[n];
  const float4* base = (const float4*)xw;
  size_t rowoff = (size_t)n * 64 + lane;
  float4 self = base[rowoff];
  float dd = di * di;
  float ax = self.x * dd, ay = self.y * dd, az = self.z * dd, aw = self.w * dd;
  int s = rs[n], e = rs[n + 1];
  int i = s;
  for (; i + 4 <= e; i += 4) {
    int s0 = csrc[i], s1 = csrc[i + 1], s2 = csrc[i + 2], s3 = csrc[i + 3];
    float w0 = cw[i], w1 = cw[i + 1], w2 = cw[i + 2], w3 = cw[i + 3];
    float4 v0 = base[(size_t)s0 * 64 + lane];
    float4 v1 = base[(size_t)s1 * 64 + lane];
    float4 v2 = base[(size_t)s2 * 64 + lane];
    float4 v3 = base[(size_t)s3 * 64 + lane];
    ax += w0 * v0.x + w1 * v1.x + w2 * v2.x + w3 * v3.x;
    ay += w0 * v0.y + w1 * v1.y + w2 * v2.y + w3 * v3.y;
    az += w0 * v0.z + w1 * v1.z + w2 * v2.z + w3 * v3.z;
    aw += w0 * v0.w + w1 * v1.w + w2 * v2.w + w3 * v3.w;
  }
  for (; i < e; ++i) {
    float w0 = cw[i];
    float4 v0 = base[(size_t)csrc[i] * 64 + lane];
    ax += w0 * v0.x;
    ay += w0 * v0.y;
    az += w0 * v0.z;
    aw += w0 * v0.w;
  }
  float4 b = ((const float4*)bias)[lane];
  ax = fmaxf(ax + b.x, 0.f);
  ay = fmaxf(ay + b.y, 0.f);
  az = fmaxf(az + b.z, 0.f);
  aw = fmaxf(aw + b.w, 0.f);
  if (MODE == 1) {
    float4 r;
    r.x = ax; r.y = ay; r.z = az; r.w = aw;
    ((float4*)xf32)[rowoff] = r;
  } else {
    ushort4 h, l;
    bf16_split(ax, h.x, l.x);
    bf16_split(ay, h.y, l.y);
    bf16_split(az, h.z, l.z);
    bf16_split(aw, h.w, l.w);
    ((ushort4*)xhi)[rowoff] = h;
    ((ushort4*)xlo)[rowoff] = l;
  }
}

// ---------------- pooling ----------------
__device__ __forceinline__ int lower_bound_dev(const int* a, int n, int key) {
  int lo = 0, hi = n;
  while (lo < hi) {
    int mid = (lo + hi) >> 1;
    if (a[mid] < key) lo = mid + 1; else hi = mid;
  }
  return lo;
}

__global__ __launch_bounds__(256) void pool_kernel(
    const float* __restrict__ x, const int* __restrict__ batch,
    float* __restrict__ h) {
  int g = blockIdx.x;
  int d = threadIdx.x;
  int start = lower_bound_dev(batch, N_NODES, g);
  int end = lower_bound_dev(batch, N_NODES, g + 1);
  float sum = 0.f, mx = 0.f;
  for (int i = start; i < end; ++i) {
    float v = x[(size_t)i * DIM + d];
    sum += v;
    mx = fmaxf(mx, v);
  }
  float cnt = (float)(end - start);
  h[(size_t)g * (2 * DIM) + d] = sum / fmaxf(cnt, 1.0f);
  h[(size_t)g * (2 * DIM) + DIM + d] = mx;
}

// ---------------- FC head ----------------
__global__ __launch_bounds__(256) void fc_kernel(
    const float* __restrict__ h, const float* __restrict__ fc1_w,
    const float* __restrict__ fc1_b, const float* __restrict__ fc2_w,
    const float* __restrict__ fc2_b, float* __restrict__ out) {
  int g = blockIdx.x;
  int j = threadIdx.x;
  __shared__ float hs[2 * DIM];
  __shared__ float s0[256], s1[256];
  hs[j] = h[(size_t)g * (2 * DIM) + j];
  hs[j + 256] = h[(size_t)g * (2 * DIM) + 256 + j];
  __syncthreads();
  float acc = fc1_b[j];
  for (int k = 0; k < 2 * DIM; ++k) acc += hs[k] * fc1_w[(size_t)k * DIM + j];
  float r = fmaxf(acc, 0.0f);
  s0[j] = r * fc2_w[j * 2 + 0];
  s1[j] = r * fc2_w[j * 2 + 1];
  __syncthreads();
  for (int off = 128; off > 0; off >>= 1) {
    if (j < off) { s0[j] += s0[j + off]; s1[j] += s1[j + off]; }
    __syncthreads();
  }
  if (j == 0) {
    out[g * 2 + 0] = s0[0] + fc2_b[0];
    out[g * 2 + 1] = s1[0] + fc2_b[1];
  }
}

extern "C" void kernel_launch(void* const* d_in, const int* in_sizes, int n_in,
                              void* d_out, int out_size, void* d_ws, size_t ws_size,
                              hipStream_t stream) {
  const float* emb_x = (const float*)d_in[0];
  const int* eidx = (const int*)d_in[1];
  const int* esrc = eidx;
  const int* edst = eidx + N_EDGES;
  const float* ew = (const float*)d_in[2];
  const int* batch = (const int*)d_in[3];
  const float* W1 = (const float*)d_in[4];
  const float* b1 = (const float*)d_in[5];
  const float* W2 = (const float*)d_in[6];
  const float* b2 = (const float*)d_in[7];
  const float* W3 = (const float*)d_in[8];
  const float* b3 = (const float*)d_in[9];
  const float* fc1_w = (const float*)d_in[10];
  const float* fc1_b = (const float*)d_in[11];
  const float* fc2_w = (const float*)d_in[12];
  const float* fc2_b = (const float*)d_in[13];
  float* out = (float*)d_out;

  char* ws = (char*)d_ws;
  size_t off = 0;
  auto take = [&](size_t bytes) -> char* {
    char* p = ws + off;
    off = (off + bytes + 255) & ~(size_t)255;
    return p;
  };
  float* XW = (float*)take((size_t)N_PAD * DIM * 4);      // gemm out (f32 gather table)
  ushort* Xhi = (ushort*)take((size_t)N_PAD * DIM * 2);   // bf16 hi  (aliased by Xf32)
  ushort* Xlo = (ushort*)take((size_t)N_PAD * DIM * 2);   // bf16 lo
  float* Xf32 = (float*)Xhi;  // layer-3 output aliases hi+lo region (both dead then)
  ushort* WT = (ushort*)take((size_t)6 * 256 * 256 * 2);  // 3x (hi,lo) transposed weights
  float* deg = (float*)take(N_NODES * 4);
  float* dinv = (float*)take(N_NODES * 4);
  int* counts = (int*)take(N_NODES * 4);
  int* rs = (int*)take((N_NODES + 1) * 4);
  int* cursor = (int*)take(N_NODES * 4);
  int* blockSums = (int*)take(64 * 4);
  int* csrc = (int*)take(N_EDGES * 4);
  float* cw = (float*)take(N_EDGES * 4);
  float* h = (float*)take((size_t)N_GRAPHS * 2 * DIM * 4);

  hipMemsetAsync(deg, 0, N_NODES * 4, stream);
  hipMemsetAsync(counts, 0, N_NODES * 4, stream);

  int eblocks = (N_EDGES + 255) / 256;
  int nblocks = (N_NODES + 255) / 256;

  deg_count_kernel<<<eblocks, 256, 0, stream>>>(edst, ew, deg, counts);
  dinv_kernel<<<nblocks, 256, 0, stream>>>(deg, dinv);
  scan_phaseA<<<SCAN_BLOCKS, 256, 0, stream>>>(counts, blockSums);
  scan_phaseB<<<1, 64, 0, stream>>>(blockSums, rs);
  scan_phaseC<<<SCAN_BLOCKS, 256, 0, stream>>>(counts, blockSums, rs, cursor);
  fill_kernel<<<eblocks, 256, 0, stream>>>(esrc, edst, ew, dinv, cursor, csrc, cw);

  // input split + weight prep
  split_x_kernel<<<(N_NODES * DIM / 4 + 255) / 256, 256, 0, stream>>>(
      emb_x, Xhi, Xlo, N_NODES * DIM / 4);
  prep_w_kernel<<<dim3(256, 3), 256, 0, stream>>>(W1, W2, W3, WT);

  ushort* W1h = WT + 0 * 65536; ushort* W1l = WT + 1 * 65536;
  ushort* W2h = WT + 2 * 65536; ushort* W2l = WT + 3 * 65536;
  ushort* W3h = WT + 4 * 65536; ushort* W3l = WT + 5 * 65536;

  dim3 ggrid(N_PAD / BM, DIM / BN);  // (391, 2)

  // layer 1
  gemm_mfma<<<ggrid, 256, 0, stream>>>(Xhi, Xlo, W1h, W1l, XW, N_NODES);
  spmm4<0><<<N_NODES / 4, 256, 0, stream>>>(XW, rs, csrc, cw, dinv, b1, nullptr, Xhi, Xlo);
  // layer 2
  gemm_mfma<<<ggrid, 256, 0, stream>>>(Xhi, Xlo, W2h, W2l, XW, N_NODES);
  spmm4<0><<<N_NODES / 4, 256, 0, stream>>>(XW, rs, csrc, cw, dinv, b2, nullptr, Xhi, Xlo);
  // layer 3
  gemm_mfma<<<ggrid, 256, 0, stream>>>(Xhi, Xlo, W3h, W3l, XW, N_NODES);
  spmm4<1><<<N_NODES / 4, 256, 0, stream>>>(XW, rs, csrc, cw, dinv, b3, Xf32, nullptr, nullptr);

  pool_kernel<<<N_GRAPHS, 256, 0, stream>>>(Xf32, batch, h);
  fc_kernel<<<N_GRAPHS, 256, 0, stream>>>(h, fc1_w, fc1_b, fc2_w, fc2_b, out);
}

// Round 3
// 726.202 us; speedup vs baseline: 1.6451x; 1.0860x over previous
//
#include <hip/hip_runtime.h>
#include <math.h>

#define N_NODES 50000
#define N_PAD 50048          // padded rows for MFMA staging (multiple of 128 above 50000)
#define N_EDGES 800000
#define DIM 256
#define N_GRAPHS 128

using f32x4 = __attribute__((ext_vector_type(4))) float;
using s16x8 = __attribute__((ext_vector_type(8))) short;

// ---------------- degree + counts ----------------
__global__ __launch_bounds__(256) void deg_count_kernel(
    const int* __restrict__ dst, const float* __restrict__ ew,
    float* __restrict__ deg, int* __restrict__ counts) {
  int e = blockIdx.x * 256 + threadIdx.x;
  if (e < N_EDGES) {
    int d = dst[e];
    atomicAdd(&deg[d], ew[e]);
    atomicAdd(&counts[d], 1);
  }
}

__global__ __launch_bounds__(256) void dinv_kernel(
    const float* __restrict__ deg, float* __restrict__ dinv) {
  int n = blockIdx.x * 256 + threadIdx.x;
  if (n < N_NODES) {
    float d = deg[n] + 1.0f;
    dinv[n] = 1.0f / sqrtf(d);
  }
}

// ---------------- exclusive scan (3 phases) ----------------
#define SCAN_CHUNK 1024
#define SCAN_BLOCKS ((N_NODES + SCAN_CHUNK - 1) / SCAN_CHUNK)

__global__ __launch_bounds__(256) void scan_phaseA(
    const int* __restrict__ counts, int* __restrict__ blockSums) {
  __shared__ int sdata[256];
  int b = blockIdx.x, t = threadIdx.x;
  int base = b * SCAN_CHUNK + t * 4;
  int s = 0;
#pragma unroll
  for (int i = 0; i < 4; ++i) {
    int idx = base + i;
    if (idx < N_NODES) s += counts[idx];
  }
  sdata[t] = s;
  __syncthreads();
  for (int off = 128; off > 0; off >>= 1) {
    if (t < off) sdata[t] += sdata[t + off];
    __syncthreads();
  }
  if (t == 0) blockSums[b] = sdata[0];
}

__global__ void scan_phaseB(int* __restrict__ blockSums, int* __restrict__ rs) {
  if (threadIdx.x == 0 && blockIdx.x == 0) {
    int acc = 0;
    for (int i = 0; i < SCAN_BLOCKS; ++i) {
      int v = blockSums[i];
      blockSums[i] = acc;
      acc += v;
    }
    rs[N_NODES] = acc;
  }
}

__global__ __launch_bounds__(256) void scan_phaseC(
    const int* __restrict__ counts, const int* __restrict__ blockSums,
    int* __restrict__ rs, int* __restrict__ cursor) {
  __shared__ int sdata[256];
  int b = blockIdx.x, t = threadIdx.x;
  int base = b * SCAN_CHUNK + t * 4;
  int v[4];
  int s = 0;
#pragma unroll
  for (int i = 0; i < 4; ++i) {
    int idx = base + i;
    v[i] = (idx < N_NODES) ? counts[idx] : 0;
    s += v[i];
  }
  sdata[t] = s;
  __syncthreads();
  for (int off = 1; off < 256; off <<= 1) {
    int x = (t >= off) ? sdata[t - off] : 0;
    __syncthreads();
    sdata[t] += x;
    __syncthreads();
  }
  int excl = (t == 0) ? 0 : sdata[t - 1];
  int o = blockSums[b] + excl;
#pragma unroll
  for (int i = 0; i < 4; ++i) {
    int idx = base + i;
    if (idx < N_NODES) { rs[idx] = o; cursor[idx] = o; }
    o += v[i];
  }
}

// ---------------- CSR fill ----------------
__global__ __launch_bounds__(256) void fill_kernel(
    const int* __restrict__ src, const int* __restrict__ dst,
    const float* __restrict__ ew, const float* __restrict__ dinv,
    int* __restrict__ cursor, int* __restrict__ csrc, float* __restrict__ cw) {
  int e = blockIdx.x * 256 + threadIdx.x;
  if (e < N_EDGES) {
    int s = src[e], d = dst[e];
    float norm = dinv[s] * ew[e] * dinv[d];
    int p = atomicAdd(&cursor[d], 1);
    csrc[p] = s;
    cw[p] = norm;
  }
}

// ---------------- f32 -> bf16 hi/lo split helpers ----------------
__device__ __forceinline__ void bf16_split(float f, ushort& hh, ushort& ll) {
  unsigned u = __float_as_uint(f);
  unsigned r = u + 0x7FFFu + ((u >> 16) & 1u);
  hh = (ushort)(r >> 16);
  float hf = __uint_as_float(((unsigned)hh) << 16);
  float d = f - hf;
  unsigned u2 = __float_as_uint(d);
  unsigned r2 = u2 + 0x7FFFu + ((u2 >> 16) & 1u);
  ll = (ushort)(r2 >> 16);
}

__global__ __launch_bounds__(256) void split_x_kernel(
    const float* __restrict__ x, ushort* __restrict__ hi, ushort* __restrict__ lo,
    int n4) {
  int i = blockIdx.x * 256 + threadIdx.x;
  if (i >= n4) return;
  float4 v = ((const float4*)x)[i];
  ushort4 h, l;
  bf16_split(v.x, h.x, l.x);
  bf16_split(v.y, h.y, l.y);
  bf16_split(v.z, h.z, l.z);
  bf16_split(v.w, h.w, l.w);
  ((ushort4*)hi)[i] = h;
  ((ushort4*)lo)[i] = l;
}

// transpose + split weights: W [K=256][N=256] f32 -> Wt_hi/Wt_lo [N][K] bf16
__global__ __launch_bounds__(256) void prep_w_kernel(
    const float* __restrict__ W1, const float* __restrict__ W2, const float* __restrict__ W3,
    ushort* __restrict__ wt) {
  int k = blockIdx.x;
  int w = blockIdx.y;
  int n = threadIdx.x;
  const float* W = (w == 0) ? W1 : (w == 1) ? W2 : W3;
  float v = W[k * 256 + n];
  ushort h, l;
  bf16_split(v, h, l);
  ushort* hplane = wt + (size_t)w * 2 * 256 * 256;
  ushort* lplane = hplane + 256 * 256;
  hplane[n * 256 + k] = h;
  lplane[n * 256 + k] = l;
}

// ---------------- split-bf16 MFMA GEMM ----------------
// C[M,256] f32 = (Ahi+Alo)[M,256] @ W[256,256]  as  Ahi@Wh + Alo@Wh + Ahi@Wl
// BM=128, BN=256 (full width, A read once), BK=32, 256 threads, acc[4][8].
// LDS layout is kblk-major: slot = kblk*ROWS + row, 16B per slot, so each
// 16-lane MFMA fragment group reads CONSECUTIVE 16B slots -> conflict-free.
#define GBM 128
#define GBN 256
#define GBK 32

__device__ __forceinline__ void gload16(const void* g, void* l) {
  __builtin_amdgcn_global_load_lds(
      (const __attribute__((address_space(1))) void*)g,
      (__attribute__((address_space(3))) void*)l, 16, 0, 0);
}

__global__ __launch_bounds__(256) void gemm_mfma(
    const ushort* __restrict__ Ahi, const ushort* __restrict__ Alo,  // [N_PAD][256]
    const ushort* __restrict__ Wth, const ushort* __restrict__ Wtl,  // [256][256] n-major
    float* __restrict__ C, int M) {
  __shared__ ushort Asl[GBM * GBK];  // 8KB : slot = kblk*128 + row
  __shared__ ushort Bsl[GBN * GBK];  // 16KB: slot = kblk*256 + row
  int tid = threadIdx.x;
  int bm = blockIdx.x * GBM;
  int wave = tid >> 6, lane = tid & 63;
  int wr = (wave >> 1) * 64;    // 0 / 64
  int wc = (wave & 1) * 128;    // 0 / 128
  int l15 = lane & 15;
  int lkb = lane >> 4;          // kblk 0..3 (8 ushorts each)

  f32x4 acc[4][8];
#pragma unroll
  for (int i = 0; i < 4; ++i)
#pragma unroll
    for (int j = 0; j < 8; ++j) acc[i][j] = (f32x4){0.f, 0.f, 0.f, 0.f};

  for (int s = 0; s < 24; ++s) {
    int pass = s >> 3;
    int k0 = (s & 7) * GBK;
    const ushort* As = (pass == 1) ? Alo : Ahi;
    const ushort* Bs = (pass == 2) ? Wtl : Wth;
    // stage A: 512 slots (128 rows x 4 kblks), 2 iters
#pragma unroll
    for (int it = 0; it < 2; ++it) {
      int slot = it * 256 + tid;
      int row = slot & 127, kb = slot >> 7;
      gload16(As + (size_t)(bm + row) * 256 + k0 + kb * 8, Asl + slot * 8);
    }
    // stage B: 1024 slots (256 rows x 4 kblks), 4 iters
#pragma unroll
    for (int it = 0; it < 4; ++it) {
      int slot = it * 256 + tid;
      int row = slot & 255, kb = slot >> 8;
      gload16(Bs + (size_t)row * 256 + k0 + kb * 8, Bsl + slot * 8);
    }
    __syncthreads();
    s16x8 af[4], bf[8];
#pragma unroll
    for (int f = 0; f < 4; ++f)
      af[f] = *(const s16x8*)(Asl + (lkb * 128 + wr + f * 16 + l15) * 8);
#pragma unroll
    for (int f = 0; f < 8; ++f)
      bf[f] = *(const s16x8*)(Bsl + (lkb * 256 + wc + f * 16 + l15) * 8);
#pragma unroll
    for (int i = 0; i < 4; ++i)
#pragma unroll
      for (int j = 0; j < 8; ++j)
        acc[i][j] = __builtin_amdgcn_mfma_f32_16x16x32_bf16(af[i], bf[j], acc[i][j], 0, 0, 0);
    __syncthreads();
  }

#pragma unroll
  for (int i = 0; i < 4; ++i) {
    int rbase = bm + wr + i * 16 + (lane >> 4) * 4;
#pragma unroll
    for (int j = 0; j < 8; ++j) {
      int col = wc + j * 16 + l15;
#pragma unroll
      for (int r = 0; r < 4; ++r) {
        int row = rbase + r;
        if (row < M) C[(size_t)row * 256 + col] = acc[i][j][r];
      }
    }
  }
}

// ---------------- SpMM: 1 wave per node, float4 lanes, 8-edge unroll ----------------
template <int MODE>
__global__ __launch_bounds__(256) void spmm4(
    const float* __restrict__ xw, const int* __restrict__ rs,
    const int* __restrict__ csrc, const float* __restrict__ cw,
    const float* __restrict__ dinv, const float* __restrict__ bias,
    float* __restrict__ xf32, ushort* __restrict__ xhi, ushort* __restrict__ xlo) {
  int wave = threadIdx.x >> 6, lane = threadIdx.x & 63;
  int n = blockIdx.x * 4 + wave;  // 50000 = 12500*4 exact
  float di = dinv[n];
  const float4* base = (const float4*)xw;
  size_t rowoff = (size_t)n * 64 + lane;
  float4 self = base[rowoff];
  float dd = di * di;
  float ax = self.x * dd, ay = self.y * dd, az = self.z * dd, aw = self.w * dd;
  int s = rs[n], e = rs[n + 1];
  int i = s;
  for (; i + 8 <= e; i += 8) {
    int idx[8];
    float w[8];
    float4 v[8];
#pragma unroll
    for (int u = 0; u < 8; ++u) { idx[u] = csrc[i + u]; w[u] = cw[i + u]; }
#pragma unroll
    for (int u = 0; u < 8; ++u) v[u] = base[(size_t)idx[u] * 64 + lane];
#pragma unroll
    for (int u = 0; u < 8; ++u) {
      ax += w[u] * v[u].x;
      ay += w[u] * v[u].y;
      az += w[u] * v[u].z;
      aw += w[u] * v[u].w;
    }
  }
  for (; i + 4 <= e; i += 4) {
    int idx[4];
    float w[4];
    float4 v[4];
#pragma unroll
    for (int u = 0; u < 4; ++u) { idx[u] = csrc[i + u]; w[u] = cw[i + u]; }
#pragma unroll
    for (int u = 0; u < 4; ++u) v[u] = base[(size_t)idx[u] * 64 + lane];
#pragma unroll
    for (int u = 0; u < 4; ++u) {
      ax += w[u] * v[u].x;
      ay += w[u] * v[u].y;
      az += w[u] * v[u].z;
      aw += w[u] * v[u].w;
    }
  }
  for (; i < e; ++i) {
    float w0 = cw[i];
    float4 v0 = base[(size_t)csrc[i] * 64 + lane];
    ax += w0 * v0.x;
    ay += w0 * v0.y;
    az += w0 * v0.z;
    aw += w0 * v0.w;
  }
  float4 b = ((const float4*)bias)[lane];
  ax = fmaxf(ax + b.x, 0.f);
  ay = fmaxf(ay + b.y, 0.f);
  az = fmaxf(az + b.z, 0.f);
  aw = fmaxf(aw + b.w, 0.f);
  if (MODE == 1) {
    float4 r;
    r.x = ax; r.y = ay; r.z = az; r.w = aw;
    ((float4*)xf32)[rowoff] = r;
  } else {
    ushort4 h, l;
    bf16_split(ax, h.x, l.x);
    bf16_split(ay, h.y, l.y);
    bf16_split(az, h.z, l.z);
    bf16_split(aw, h.w, l.w);
    ((ushort4*)xhi)[rowoff] = h;
    ((ushort4*)xlo)[rowoff] = l;
  }
}

// ---------------- pooling: grid (graph, dim-chunk), 4 node-lanes ----------------
__device__ __forceinline__ int lower_bound_dev(const int* a, int n, int key) {
  int lo = 0, hi = n;
  while (lo < hi) {
    int mid = (lo + hi) >> 1;
    if (a[mid] < key) lo = mid + 1; else hi = mid;
  }
  return lo;
}

__global__ __launch_bounds__(256) void pool_kernel(
    const float* __restrict__ x, const int* __restrict__ batch,
    float* __restrict__ h) {
  int g = blockIdx.x;
  int dchunk = blockIdx.y;          // 0..3
  int t = threadIdx.x;
  int dl = t & 63;                  // dim within chunk
  int nl = t >> 6;                  // node lane 0..3
  int d = dchunk * 64 + dl;
  int start = lower_bound_dev(batch, N_NODES, g);
  int end = lower_bound_dev(batch, N_NODES, g + 1);
  float sum = 0.f, mx = 0.f;
  for (int i = start + nl; i < end; i += 4) {
    float v = x[(size_t)i * DIM + d];
    sum += v;
    mx = fmaxf(mx, v);
  }
  __shared__ float ssum[4][64];
  __shared__ float smax[4][64];
  ssum[nl][dl] = sum;
  smax[nl][dl] = mx;
  __syncthreads();
  if (nl == 0) {
    sum = ssum[0][dl] + ssum[1][dl] + ssum[2][dl] + ssum[3][dl];
    mx = fmaxf(fmaxf(smax[0][dl], smax[1][dl]), fmaxf(smax[2][dl], smax[3][dl]));
    float cnt = (float)(end - start);
    h[(size_t)g * (2 * DIM) + d] = sum / fmaxf(cnt, 1.0f);
    h[(size_t)g * (2 * DIM) + DIM + d] = mx;
  }
}

// ---------------- FC head ----------------
__global__ __launch_bounds__(256) void fc_kernel(
    const float* __restrict__ h, const float* __restrict__ fc1_w,
    const float* __restrict__ fc1_b, const float* __restrict__ fc2_w,
    const float* __restrict__ fc2_b, float* __restrict__ out) {
  int g = blockIdx.x;
  int j = threadIdx.x;
  __shared__ float hs[2 * DIM];
  __shared__ float s0[256], s1[256];
  hs[j] = h[(size_t)g * (2 * DIM) + j];
  hs[j + 256] = h[(size_t)g * (2 * DIM) + 256 + j];
  __syncthreads();
  float acc = fc1_b[j];
  for (int k = 0; k < 2 * DIM; ++k) acc += hs[k] * fc1_w[(size_t)k * DIM + j];
  float r = fmaxf(acc, 0.0f);
  s0[j] = r * fc2_w[j * 2 + 0];
  s1[j] = r * fc2_w[j * 2 + 1];
  __syncthreads();
  for (int off = 128; off > 0; off >>= 1) {
    if (j < off) { s0[j] += s0[j + off]; s1[j] += s1[j + off]; }
    __syncthreads();
  }
  if (j == 0) {
    out[g * 2 + 0] = s0[0] + fc2_b[0];
    out[g * 2 + 1] = s1[0] + fc2_b[1];
  }
}

extern "C" void kernel_launch(void* const* d_in, const int* in_sizes, int n_in,
                              void* d_out, int out_size, void* d_ws, size_t ws_size,
                              hipStream_t stream) {
  const float* emb_x = (const float*)d_in[0];
  const int* eidx = (const int*)d_in[1];
  const int* esrc = eidx;
  const int* edst = eidx + N_EDGES;
  const float* ew = (const float*)d_in[2];
  const int* batch = (const int*)d_in[3];
  const float* W1 = (const float*)d_in[4];
  const float* b1 = (const float*)d_in[5];
  const float* W2 = (const float*)d_in[6];
  const float* b2 = (const float*)d_in[7];
  const float* W3 = (const float*)d_in[8];
  const float* b3 = (const float*)d_in[9];
  const float* fc1_w = (const float*)d_in[10];
  const float* fc1_b = (const float*)d_in[11];
  const float* fc2_w = (const float*)d_in[12];
  const float* fc2_b = (const float*)d_in[13];
  float* out = (float*)d_out;

  char* ws = (char*)d_ws;
  size_t off = 0;
  auto take = [&](size_t bytes) -> char* {
    char* p = ws + off;
    off = (off + bytes + 255) & ~(size_t)255;
    return p;
  };
  float* XW = (float*)take((size_t)N_PAD * DIM * 4);
  ushort* Xhi = (ushort*)take((size_t)N_PAD * DIM * 2);
  ushort* Xlo = (ushort*)take((size_t)N_PAD * DIM * 2);
  float* Xf32 = (float*)Xhi;  // layer-3 f32 output aliases hi+lo region
  ushort* WT = (ushort*)take((size_t)6 * 256 * 256 * 2);
  float* deg = (float*)take(N_NODES * 4);
  float* dinv = (float*)take(N_NODES * 4);
  int* counts = (int*)take(N_NODES * 4);
  int* rs = (int*)take((N_NODES + 1) * 4);
  int* cursor = (int*)take(N_NODES * 4);
  int* blockSums = (int*)take(64 * 4);
  int* csrc = (int*)take(N_EDGES * 4);
  float* cw = (float*)take(N_EDGES * 4);
  float* h = (float*)take((size_t)N_GRAPHS * 2 * DIM * 4);

  hipMemsetAsync(deg, 0, N_NODES * 4, stream);
  hipMemsetAsync(counts, 0, N_NODES * 4, stream);
  // zero the padded tail rows of Xhi/Xlo (read by gemm as A rows >= N_NODES)
  hipMemsetAsync(Xhi + (size_t)N_NODES * DIM, 0, (size_t)(N_PAD - N_NODES) * DIM * 2, stream);
  hipMemsetAsync(Xlo + (size_t)N_NODES * DIM, 0, (size_t)(N_PAD - N_NODES) * DIM * 2, stream);

  int eblocks = (N_EDGES + 255) / 256;
  int nblocks = (N_NODES + 255) / 256;

  deg_count_kernel<<<eblocks, 256, 0, stream>>>(edst, ew, deg, counts);
  dinv_kernel<<<nblocks, 256, 0, stream>>>(deg, dinv);
  scan_phaseA<<<SCAN_BLOCKS, 256, 0, stream>>>(counts, blockSums);
  scan_phaseB<<<1, 64, 0, stream>>>(blockSums, rs);
  scan_phaseC<<<SCAN_BLOCKS, 256, 0, stream>>>(counts, blockSums, rs, cursor);
  fill_kernel<<<eblocks, 256, 0, stream>>>(esrc, edst, ew, dinv, cursor, csrc, cw);

  split_x_kernel<<<(N_NODES * DIM / 4 + 255) / 256, 256, 0, stream>>>(
      emb_x, Xhi, Xlo, N_NODES * DIM / 4);
  prep_w_kernel<<<dim3(256, 3), 256, 0, stream>>>(W1, W2, W3, WT);

  ushort* W1h = WT + 0 * 65536; ushort* W1l = WT + 1 * 65536;
  ushort* W2h = WT + 2 * 65536; ushort* W2l = WT + 3 * 65536;
  ushort* W3h = WT + 4 * 65536; ushort* W3l = WT + 5 * 65536;

  dim3 ggrid(N_PAD / GBM, 1);  // 391 blocks, full N per block

  // layer 1
  gemm_mfma<<<ggrid, 256, 0, stream>>>(Xhi, Xlo, W1h, W1l, XW, N_NODES);
  spmm4<0><<<N_NODES / 4, 256, 0, stream>>>(XW, rs, csrc, cw, dinv, b1, nullptr, Xhi, Xlo);
  // layer 2
  gemm_mfma<<<ggrid, 256, 0, stream>>>(Xhi, Xlo, W2h, W2l, XW, N_NODES);
  spmm4<0><<<N_NODES / 4, 256, 0, stream>>>(XW, rs, csrc, cw, dinv, b2, nullptr, Xhi, Xlo);
  // layer 3
  gemm_mfma<<<ggrid, 256, 0, stream>>>(Xhi, Xlo, W3h, W3l, XW, N_NODES);
  spmm4<1><<<N_NODES / 4, 256, 0, stream>>>(XW, rs, csrc, cw, dinv, b3, Xf32, nullptr, nullptr);

  pool_kernel<<<dim3(N_GRAPHS, 4), 256, 0, stream>>>(Xf32, batch, h);
  fc_kernel<<<N_GRAPHS, 256, 0, stream>>>(h, fc1_w, fc1_b, fc2_w, fc2_b, out);
}

// Round 4
// 639.201 us; speedup vs baseline: 1.8690x; 1.1361x over previous
//
#include <hip/hip_runtime.h>
#include <math.h>

#define N_NODES 50000
#define N_PAD 50048          // padded rows for MFMA staging (multiple of 128 above 50000)
#define N_EDGES 800000
#define DIM 256
#define N_GRAPHS 128

using f32x4 = __attribute__((ext_vector_type(4))) float;
using s16x8 = __attribute__((ext_vector_type(8))) short;

// ---------------- degree + counts ----------------
__global__ __launch_bounds__(256) void deg_count_kernel(
    const int* __restrict__ dst, const float* __restrict__ ew,
    float* __restrict__ deg, int* __restrict__ counts) {
  int e = blockIdx.x * 256 + threadIdx.x;
  if (e < N_EDGES) {
    int d = dst[e];
    atomicAdd(&deg[d], ew[e]);
    atomicAdd(&counts[d], 1);
  }
}

__global__ __launch_bounds__(256) void dinv_kernel(
    const float* __restrict__ deg, float* __restrict__ dinv) {
  int n = blockIdx.x * 256 + threadIdx.x;
  if (n < N_NODES) {
    float d = deg[n] + 1.0f;
    dinv[n] = 1.0f / sqrtf(d);
  }
}

// ---------------- exclusive scan (3 phases) ----------------
#define SCAN_CHUNK 1024
#define SCAN_BLOCKS ((N_NODES + SCAN_CHUNK - 1) / SCAN_CHUNK)

__global__ __launch_bounds__(256) void scan_phaseA(
    const int* __restrict__ counts, int* __restrict__ blockSums) {
  __shared__ int sdata[256];
  int b = blockIdx.x, t = threadIdx.x;
  int base = b * SCAN_CHUNK + t * 4;
  int s = 0;
#pragma unroll
  for (int i = 0; i < 4; ++i) {
    int idx = base + i;
    if (idx < N_NODES) s += counts[idx];
  }
  sdata[t] = s;
  __syncthreads();
  for (int off = 128; off > 0; off >>= 1) {
    if (t < off) sdata[t] += sdata[t + off];
    __syncthreads();
  }
  if (t == 0) blockSums[b] = sdata[0];
}

__global__ void scan_phaseB(int* __restrict__ blockSums, int* __restrict__ rs) {
  if (threadIdx.x == 0 && blockIdx.x == 0) {
    int acc = 0;
    for (int i = 0; i < SCAN_BLOCKS; ++i) {
      int v = blockSums[i];
      blockSums[i] = acc;
      acc += v;
    }
    rs[N_NODES] = acc;
  }
}

__global__ __launch_bounds__(256) void scan_phaseC(
    const int* __restrict__ counts, const int* __restrict__ blockSums,
    int* __restrict__ rs, int* __restrict__ cursor) {
  __shared__ int sdata[256];
  int b = blockIdx.x, t = threadIdx.x;
  int base = b * SCAN_CHUNK + t * 4;
  int v[4];
  int s = 0;
#pragma unroll
  for (int i = 0; i < 4; ++i) {
    int idx = base + i;
    v[i] = (idx < N_NODES) ? counts[idx] : 0;
    s += v[i];
  }
  sdata[t] = s;
  __syncthreads();
  for (int off = 1; off < 256; off <<= 1) {
    int x = (t >= off) ? sdata[t - off] : 0;
    __syncthreads();
    sdata[t] += x;
    __syncthreads();
  }
  int excl = (t == 0) ? 0 : sdata[t - 1];
  int o = blockSums[b] + excl;
#pragma unroll
  for (int i = 0; i < 4; ++i) {
    int idx = base + i;
    if (idx < N_NODES) { rs[idx] = o; cursor[idx] = o; }
    o += v[i];
  }
}

// ---------------- CSR fill ----------------
__global__ __launch_bounds__(256) void fill_kernel(
    const int* __restrict__ src, const int* __restrict__ dst,
    const float* __restrict__ ew, const float* __restrict__ dinv,
    int* __restrict__ cursor, int* __restrict__ csrc, float* __restrict__ cw) {
  int e = blockIdx.x * 256 + threadIdx.x;
  if (e < N_EDGES) {
    int s = src[e], d = dst[e];
    float norm = dinv[s] * ew[e] * dinv[d];
    int p = atomicAdd(&cursor[d], 1);
    csrc[p] = s;
    cw[p] = norm;
  }
}

// ---------------- bf16 helpers ----------------
__device__ __forceinline__ ushort bf16_hi(float f) {
  unsigned u = __float_as_uint(f);
  return (ushort)((u + 0x7FFFu + ((u >> 16) & 1u)) >> 16);
}
__device__ __forceinline__ float bf16_up(ushort h) {
  return __uint_as_float(((unsigned)h) << 16);
}
__device__ __forceinline__ void bf16_split(float f, ushort& hh, ushort& ll) {
  hh = bf16_hi(f);
  float d = f - bf16_up(hh);
  ll = bf16_hi(d);
}

__global__ __launch_bounds__(256) void split_x_kernel(
    const float* __restrict__ x, ushort* __restrict__ hi, ushort* __restrict__ lo,
    int n4) {
  int i = blockIdx.x * 256 + threadIdx.x;
  if (i >= n4) return;
  float4 v = ((const float4*)x)[i];
  ushort4 h, l;
  bf16_split(v.x, h.x, l.x);
  bf16_split(v.y, h.y, l.y);
  bf16_split(v.z, h.z, l.z);
  bf16_split(v.w, h.w, l.w);
  ((ushort4*)hi)[i] = h;
  ((ushort4*)lo)[i] = l;
}

// transpose + split weights: W [K=256][N=256] f32 -> Wt_hi/Wt_lo [N][K] bf16
__global__ __launch_bounds__(256) void prep_w_kernel(
    const float* __restrict__ W1, const float* __restrict__ W2, const float* __restrict__ W3,
    ushort* __restrict__ wt) {
  int k = blockIdx.x;
  int w = blockIdx.y;
  int n = threadIdx.x;
  const float* W = (w == 0) ? W1 : (w == 1) ? W2 : W3;
  float v = W[k * 256 + n];
  ushort h, l;
  bf16_split(v, h, l);
  ushort* hplane = wt + (size_t)w * 2 * 256 * 256;
  ushort* lplane = hplane + 256 * 256;
  hplane[n * 256 + k] = h;
  lplane[n * 256 + k] = l;
}

// ---------------- split-bf16 MFMA GEMM, bf16 output ----------------
// XW[M,256] bf16 = round_bf16( (Ahi+Alo)[M,256] @ W[256,256] )
// passes: Ahi@Wh + Alo@Wh + Ahi@Wl  (K=768 effective)
#define GBM 128
#define GBN 256
#define GBK 32

__device__ __forceinline__ void gload16(const void* g, void* l) {
  __builtin_amdgcn_global_load_lds(
      (const __attribute__((address_space(1))) void*)g,
      (__attribute__((address_space(3))) void*)l, 16, 0, 0);
}

__global__ __launch_bounds__(256) void gemm_mfma(
    const ushort* __restrict__ Ahi, const ushort* __restrict__ Alo,  // [N_PAD][256]
    const ushort* __restrict__ Wth, const ushort* __restrict__ Wtl,  // [256][256] n-major
    ushort* __restrict__ C, int M) {
  __shared__ ushort Asl[GBM * GBK];  // 8KB : slot = kblk*128 + row
  __shared__ ushort Bsl[GBN * GBK];  // 16KB: slot = kblk*256 + row
  int tid = threadIdx.x;
  int bm = blockIdx.x * GBM;
  int wave = tid >> 6, lane = tid & 63;
  int wr = (wave >> 1) * 64;    // 0 / 64
  int wc = (wave & 1) * 128;    // 0 / 128
  int l15 = lane & 15;
  int lkb = lane >> 4;          // kblk 0..3

  f32x4 acc[4][8];
#pragma unroll
  for (int i = 0; i < 4; ++i)
#pragma unroll
    for (int j = 0; j < 8; ++j) acc[i][j] = (f32x4){0.f, 0.f, 0.f, 0.f};

  for (int s = 0; s < 24; ++s) {
    int pass = s >> 3;
    int k0 = (s & 7) * GBK;
    const ushort* As = (pass == 1) ? Alo : Ahi;
    const ushort* Bs = (pass == 2) ? Wtl : Wth;
#pragma unroll
    for (int it = 0; it < 2; ++it) {
      int slot = it * 256 + tid;
      int row = slot & 127, kb = slot >> 7;
      gload16(As + (size_t)(bm + row) * 256 + k0 + kb * 8, Asl + slot * 8);
    }
#pragma unroll
    for (int it = 0; it < 4; ++it) {
      int slot = it * 256 + tid;
      int row = slot & 255, kb = slot >> 8;
      gload16(Bs + (size_t)row * 256 + k0 + kb * 8, Bsl + slot * 8);
    }
    __syncthreads();
    s16x8 af[4], bf[8];
#pragma unroll
    for (int f = 0; f < 4; ++f)
      af[f] = *(const s16x8*)(Asl + (lkb * 128 + wr + f * 16 + l15) * 8);
#pragma unroll
    for (int f = 0; f < 8; ++f)
      bf[f] = *(const s16x8*)(Bsl + (lkb * 256 + wc + f * 16 + l15) * 8);
#pragma unroll
    for (int i = 0; i < 4; ++i)
#pragma unroll
      for (int j = 0; j < 8; ++j)
        acc[i][j] = __builtin_amdgcn_mfma_f32_16x16x32_bf16(af[i], bf[j], acc[i][j], 0, 0, 0);
    __syncthreads();
  }

#pragma unroll
  for (int i = 0; i < 4; ++i) {
    int rbase = bm + wr + i * 16 + (lane >> 4) * 4;
#pragma unroll
    for (int j = 0; j < 8; ++j) {
      int col = wc + j * 16 + l15;
#pragma unroll
      for (int r = 0; r < 4; ++r) {
        int row = rbase + r;
        if (row < M) C[(size_t)row * 256 + col] = bf16_hi(acc[i][j][r]);
      }
    }
  }
}

// ---------------- SpMM: bf16 gather table, 1 wave/node, 8-edge unroll ----------------
// MODE 0: write bf16 hi/lo of x (feeds next layer's MFMA GEMM)
// MODE 1: write f32 x (feeds pooling)
template <int MODE>
__global__ __launch_bounds__(256) void spmm4(
    const ushort* __restrict__ xw, const int* __restrict__ rs,
    const int* __restrict__ csrc, const float* __restrict__ cw,
    const float* __restrict__ dinv, const float* __restrict__ bias,
    float* __restrict__ xf32, ushort* __restrict__ xhi, ushort* __restrict__ xlo) {
  int wave = threadIdx.x >> 6, lane = threadIdx.x & 63;
  int n = blockIdx.x * 4 + wave;  // 50000 = 12500*4 exact
  float di = dinv[n];
  const ushort4* base = (const ushort4*)xw;  // 64 x ushort4 per row
  size_t rowoff = (size_t)n * 64 + lane;
  ushort4 selfh = base[rowoff];
  float dd = di * di;
  float ax = bf16_up(selfh.x) * dd, ay = bf16_up(selfh.y) * dd;
  float az = bf16_up(selfh.z) * dd, aw = bf16_up(selfh.w) * dd;
  int s = rs[n], e = rs[n + 1];
  int i = s;
  for (; i + 8 <= e; i += 8) {
    int idx[8];
    float w[8];
    ushort4 v[8];
#pragma unroll
    for (int u = 0; u < 8; ++u) { idx[u] = csrc[i + u]; w[u] = cw[i + u]; }
#pragma unroll
    for (int u = 0; u < 8; ++u) v[u] = base[(size_t)idx[u] * 64 + lane];
#pragma unroll
    for (int u = 0; u < 8; ++u) {
      ax += w[u] * bf16_up(v[u].x);
      ay += w[u] * bf16_up(v[u].y);
      az += w[u] * bf16_up(v[u].z);
      aw += w[u] * bf16_up(v[u].w);
    }
  }
  for (; i + 4 <= e; i += 4) {
    int idx[4];
    float w[4];
    ushort4 v[4];
#pragma unroll
    for (int u = 0; u < 4; ++u) { idx[u] = csrc[i + u]; w[u] = cw[i + u]; }
#pragma unroll
    for (int u = 0; u < 4; ++u) v[u] = base[(size_t)idx[u] * 64 + lane];
#pragma unroll
    for (int u = 0; u < 4; ++u) {
      ax += w[u] * bf16_up(v[u].x);
      ay += w[u] * bf16_up(v[u].y);
      az += w[u] * bf16_up(v[u].z);
      aw += w[u] * bf16_up(v[u].w);
    }
  }
  for (; i < e; ++i) {
    float w0 = cw[i];
    ushort4 v0 = base[(size_t)csrc[i] * 64 + lane];
    ax += w0 * bf16_up(v0.x);
    ay += w0 * bf16_up(v0.y);
    az += w0 * bf16_up(v0.z);
    aw += w0 * bf16_up(v0.w);
  }
  float4 b = ((const float4*)bias)[lane];
  ax = fmaxf(ax + b.x, 0.f);
  ay = fmaxf(ay + b.y, 0.f);
  az = fmaxf(az + b.z, 0.f);
  aw = fmaxf(aw + b.w, 0.f);
  if (MODE == 1) {
    float4 r;
    r.x = ax; r.y = ay; r.z = az; r.w = aw;
    ((float4*)xf32)[rowoff] = r;
  } else {
    ushort4 h, l;
    bf16_split(ax, h.x, l.x);
    bf16_split(ay, h.y, l.y);
    bf16_split(az, h.z, l.z);
    bf16_split(aw, h.w, l.w);
    ((ushort4*)xhi)[rowoff] = h;
    ((ushort4*)xlo)[rowoff] = l;
  }
}

// ---------------- pooling: grid (graph, dim-chunk), 4 node-lanes ----------------
__device__ __forceinline__ int lower_bound_dev(const int* a, int n, int key) {
  int lo = 0, hi = n;
  while (lo < hi) {
    int mid = (lo + hi) >> 1;
    if (a[mid] < key) lo = mid + 1; else hi = mid;
  }
  return lo;
}

__global__ __launch_bounds__(256) void pool_kernel(
    const float* __restrict__ x, const int* __restrict__ batch,
    float* __restrict__ h) {
  int g = blockIdx.x;
  int dchunk = blockIdx.y;
  int t = threadIdx.x;
  int dl = t & 63;
  int nl = t >> 6;
  int d = dchunk * 64 + dl;
  int start = lower_bound_dev(batch, N_NODES, g);
  int end = lower_bound_dev(batch, N_NODES, g + 1);
  float sum = 0.f, mx = 0.f;
  for (int i = start + nl; i < end; i += 4) {
    float v = x[(size_t)i * DIM + d];
    sum += v;
    mx = fmaxf(mx, v);
  }
  __shared__ float ssum[4][64];
  __shared__ float smax[4][64];
  ssum[nl][dl] = sum;
  smax[nl][dl] = mx;
  __syncthreads();
  if (nl == 0) {
    sum = ssum[0][dl] + ssum[1][dl] + ssum[2][dl] + ssum[3][dl];
    mx = fmaxf(fmaxf(smax[0][dl], smax[1][dl]), fmaxf(smax[2][dl], smax[3][dl]));
    float cnt = (float)(end - start);
    h[(size_t)g * (2 * DIM) + d] = sum / fmaxf(cnt, 1.0f);
    h[(size_t)g * (2 * DIM) + DIM + d] = mx;
  }
}

// ---------------- FC head ----------------
__global__ __launch_bounds__(256) void fc_kernel(
    const float* __restrict__ h, const float* __restrict__ fc1_w,
    const float* __restrict__ fc1_b, const float* __restrict__ fc2_w,
    const float* __restrict__ fc2_b, float* __restrict__ out) {
  int g = blockIdx.x;
  int j = threadIdx.x;
  __shared__ float hs[2 * DIM];
  __shared__ float s0[256], s1[256];
  hs[j] = h[(size_t)g * (2 * DIM) + j];
  hs[j + 256] = h[(size_t)g * (2 * DIM) + 256 + j];
  __syncthreads();
  float acc = fc1_b[j];
  for (int k = 0; k < 2 * DIM; ++k) acc += hs[k] * fc1_w[(size_t)k * DIM + j];
  float r = fmaxf(acc, 0.0f);
  s0[j] = r * fc2_w[j * 2 + 0];
  s1[j] = r * fc2_w[j * 2 + 1];
  __syncthreads();
  for (int off = 128; off > 0; off >>= 1) {
    if (j < off) { s0[j] += s0[j + off]; s1[j] += s1[j + off]; }
    __syncthreads();
  }
  if (j == 0) {
    out[g * 2 + 0] = s0[0] + fc2_b[0];
    out[g * 2 + 1] = s1[0] + fc2_b[1];
  }
}

extern "C" void kernel_launch(void* const* d_in, const int* in_sizes, int n_in,
                              void* d_out, int out_size, void* d_ws, size_t ws_size,
                              hipStream_t stream) {
  const float* emb_x = (const float*)d_in[0];
  const int* eidx = (const int*)d_in[1];
  const int* esrc = eidx;
  const int* edst = eidx + N_EDGES;
  const float* ew = (const float*)d_in[2];
  const int* batch = (const int*)d_in[3];
  const float* W1 = (const float*)d_in[4];
  const float* b1 = (const float*)d_in[5];
  const float* W2 = (const float*)d_in[6];
  const float* b2 = (const float*)d_in[7];
  const float* W3 = (const float*)d_in[8];
  const float* b3 = (const float*)d_in[9];
  const float* fc1_w = (const float*)d_in[10];
  const float* fc1_b = (const float*)d_in[11];
  const float* fc2_w = (const float*)d_in[12];
  const float* fc2_b = (const float*)d_in[13];
  float* out = (float*)d_out;

  char* ws = (char*)d_ws;
  size_t off = 0;
  auto take = [&](size_t bytes) -> char* {
    char* p = ws + off;
    off = (off + bytes + 255) & ~(size_t)255;
    return p;
  };
  ushort* XW = (ushort*)take((size_t)N_PAD * DIM * 2);    // bf16 gather table
  ushort* Xhi = (ushort*)take((size_t)N_PAD * DIM * 2);
  ushort* Xlo = (ushort*)take((size_t)N_PAD * DIM * 2);
  float* Xf32 = (float*)take((size_t)N_NODES * DIM * 4);  // layer-3 f32 out for pooling
  ushort* WT = (ushort*)take((size_t)6 * 256 * 256 * 2);
  float* deg = (float*)take(N_NODES * 4);
  float* dinv = (float*)take(N_NODES * 4);
  int* counts = (int*)take(N_NODES * 4);
  int* rs = (int*)take((N_NODES + 1) * 4);
  int* cursor = (int*)take(N_NODES * 4);
  int* blockSums = (int*)take(64 * 4);
  int* csrc = (int*)take(N_EDGES * 4);
  float* cw = (float*)take(N_EDGES * 4);
  float* h = (float*)take((size_t)N_GRAPHS * 2 * DIM * 4);

  hipMemsetAsync(deg, 0, N_NODES * 4, stream);
  hipMemsetAsync(counts, 0, N_NODES * 4, stream);
  // zero the padded tail rows of Xhi/Xlo (read by gemm as A rows >= N_NODES)
  hipMemsetAsync(Xhi + (size_t)N_NODES * DIM, 0, (size_t)(N_PAD - N_NODES) * DIM * 2, stream);
  hipMemsetAsync(Xlo + (size_t)N_NODES * DIM, 0, (size_t)(N_PAD - N_NODES) * DIM * 2, stream);

  int eblocks = (N_EDGES + 255) / 256;
  int nblocks = (N_NODES + 255) / 256;

  deg_count_kernel<<<eblocks, 256, 0, stream>>>(edst, ew, deg, counts);
  dinv_kernel<<<nblocks, 256, 0, stream>>>(deg, dinv);
  scan_phaseA<<<SCAN_BLOCKS, 256, 0, stream>>>(counts, blockSums);
  scan_phaseB<<<1, 64, 0, stream>>>(blockSums, rs);
  scan_phaseC<<<SCAN_BLOCKS, 256, 0, stream>>>(counts, blockSums, rs, cursor);
  fill_kernel<<<eblocks, 256, 0, stream>>>(esrc, edst, ew, dinv, cursor, csrc, cw);

  split_x_kernel<<<(N_NODES * DIM / 4 + 255) / 256, 256, 0, stream>>>(
      emb_x, Xhi, Xlo, N_NODES * DIM / 4);
  prep_w_kernel<<<dim3(256, 3), 256, 0, stream>>>(W1, W2, W3, WT);

  ushort* W1h = WT + 0 * 65536; ushort* W1l = WT + 1 * 65536;
  ushort* W2h = WT + 2 * 65536; ushort* W2l = WT + 3 * 65536;
  ushort* W3h = WT + 4 * 65536; ushort* W3l = WT + 5 * 65536;

  dim3 ggrid(N_PAD / GBM, 1);  // 391 blocks, full N per block

  // layer 1
  gemm_mfma<<<ggrid, 256, 0, stream>>>(Xhi, Xlo, W1h, W1l, XW, N_NODES);
  spmm4<0><<<N_NODES / 4, 256, 0, stream>>>(XW, rs, csrc, cw, dinv, b1, nullptr, Xhi, Xlo);
  // layer 2
  gemm_mfma<<<ggrid, 256, 0, stream>>>(Xhi, Xlo, W2h, W2l, XW, N_NODES);
  spmm4<0><<<N_NODES / 4, 256, 0, stream>>>(XW, rs, csrc, cw, dinv, b2, nullptr, Xhi, Xlo);
  // layer 3
  gemm_mfma<<<ggrid, 256, 0, stream>>>(Xhi, Xlo, W3h, W3l, XW, N_NODES);
  spmm4<1><<<N_NODES / 4, 256, 0, stream>>>(XW, rs, csrc, cw, dinv, b3, Xf32, nullptr, nullptr);

  pool_kernel<<<dim3(N_GRAPHS, 4), 256, 0, stream>>>(Xf32, batch, h);
  fc_kernel<<<N_GRAPHS, 256, 0, stream>>>(h, fc1_w, fc1_b, fc2_w, fc2_b, out);
}

// Round 5
// 586.992 us; speedup vs baseline: 2.0352x; 1.0889x over previous
//
#include <hip/hip_runtime.h>
#include <math.h>

#define N_NODES 50000
#define N_PAD 50048          // multiple of 64 above 50000
#define N_EDGES 800000
#define DIM 256
#define N_GRAPHS 128

using f32x4 = __attribute__((ext_vector_type(4))) float;
using s16x8 = __attribute__((ext_vector_type(8))) short;

// ---------------- degree + counts ----------------
__global__ __launch_bounds__(256) void deg_count_kernel(
    const int* __restrict__ dst, const float* __restrict__ ew,
    float* __restrict__ deg, int* __restrict__ counts) {
  int e = blockIdx.x * 256 + threadIdx.x;
  if (e < N_EDGES) {
    int d = dst[e];
    atomicAdd(&deg[d], ew[e]);
    atomicAdd(&counts[d], 1);
  }
}

__global__ __launch_bounds__(256) void dinv_kernel(
    const float* __restrict__ deg, float* __restrict__ dinv) {
  int n = blockIdx.x * 256 + threadIdx.x;
  if (n < N_NODES) {
    float d = deg[n] + 1.0f;
    dinv[n] = 1.0f / sqrtf(d);
  }
}

// ---------------- exclusive scan (3 phases) ----------------
#define SCAN_CHUNK 1024
#define SCAN_BLOCKS ((N_NODES + SCAN_CHUNK - 1) / SCAN_CHUNK)

__global__ __launch_bounds__(256) void scan_phaseA(
    const int* __restrict__ counts, int* __restrict__ blockSums) {
  __shared__ int sdata[256];
  int b = blockIdx.x, t = threadIdx.x;
  int base = b * SCAN_CHUNK + t * 4;
  int s = 0;
#pragma unroll
  for (int i = 0; i < 4; ++i) {
    int idx = base + i;
    if (idx < N_NODES) s += counts[idx];
  }
  sdata[t] = s;
  __syncthreads();
  for (int off = 128; off > 0; off >>= 1) {
    if (t < off) sdata[t] += sdata[t + off];
    __syncthreads();
  }
  if (t == 0) blockSums[b] = sdata[0];
}

__global__ void scan_phaseB(int* __restrict__ blockSums, int* __restrict__ rs) {
  if (threadIdx.x == 0 && blockIdx.x == 0) {
    int acc = 0;
    for (int i = 0; i < SCAN_BLOCKS; ++i) {
      int v = blockSums[i];
      blockSums[i] = acc;
      acc += v;
    }
    rs[N_NODES] = acc;
  }
}

__global__ __launch_bounds__(256) void scan_phaseC(
    const int* __restrict__ counts, const int* __restrict__ blockSums,
    int* __restrict__ rs, int* __restrict__ cursor) {
  __shared__ int sdata[256];
  int b = blockIdx.x, t = threadIdx.x;
  int base = b * SCAN_CHUNK + t * 4;
  int v[4];
  int s = 0;
#pragma unroll
  for (int i = 0; i < 4; ++i) {
    int idx = base + i;
    v[i] = (idx < N_NODES) ? counts[idx] : 0;
    s += v[i];
  }
  sdata[t] = s;
  __syncthreads();
  for (int off = 1; off < 256; off <<= 1) {
    int x = (t >= off) ? sdata[t - off] : 0;
    __syncthreads();
    sdata[t] += x;
    __syncthreads();
  }
  int excl = (t == 0) ? 0 : sdata[t - 1];
  int o = blockSums[b] + excl;
#pragma unroll
  for (int i = 0; i < 4; ++i) {
    int idx = base + i;
    if (idx < N_NODES) { rs[idx] = o; cursor[idx] = o; }
    o += v[i];
  }
}

// ---------------- CSR fill ----------------
__global__ __launch_bounds__(256) void fill_kernel(
    const int* __restrict__ src, const int* __restrict__ dst,
    const float* __restrict__ ew, const float* __restrict__ dinv,
    int* __restrict__ cursor, int* __restrict__ csrc, float* __restrict__ cw) {
  int e = blockIdx.x * 256 + threadIdx.x;
  if (e < N_EDGES) {
    int s = src[e], d = dst[e];
    float norm = dinv[s] * ew[e] * dinv[d];
    int p = atomicAdd(&cursor[d], 1);
    csrc[p] = s;
    cw[p] = norm;
  }
}

// ---------------- bf16 helpers ----------------
__device__ __forceinline__ ushort bf16_hi(float f) {
  unsigned u = __float_as_uint(f);
  return (ushort)((u + 0x7FFFu + ((u >> 16) & 1u)) >> 16);
}
__device__ __forceinline__ float bf16_up(ushort h) {
  return __uint_as_float(((unsigned)h) << 16);
}
__device__ __forceinline__ void bf16_split(float f, ushort& hh, ushort& ll) {
  hh = bf16_hi(f);
  float d = f - bf16_up(hh);
  ll = bf16_hi(d);
}

// round emb_x to bf16 (GEMM A input)
__global__ __launch_bounds__(256) void round_x_kernel(
    const float* __restrict__ x, ushort* __restrict__ hi, int n4) {
  int i = blockIdx.x * 256 + threadIdx.x;
  if (i >= n4) return;
  float4 v = ((const float4*)x)[i];
  ushort4 h;
  h.x = bf16_hi(v.x);
  h.y = bf16_hi(v.y);
  h.z = bf16_hi(v.z);
  h.w = bf16_hi(v.w);
  ((ushort4*)hi)[i] = h;
}

// transpose + split weights: W [K=256][N=256] f32 -> Wt_hi/Wt_lo [N][K] bf16
__global__ __launch_bounds__(256) void prep_w_kernel(
    const float* __restrict__ W1, const float* __restrict__ W2, const float* __restrict__ W3,
    ushort* __restrict__ wt) {
  int k = blockIdx.x;
  int w = blockIdx.y;
  int n = threadIdx.x;
  const float* W = (w == 0) ? W1 : (w == 1) ? W2 : W3;
  float v = W[k * 256 + n];
  ushort h, l;
  bf16_split(v, h, l);
  ushort* hplane = wt + (size_t)w * 2 * 256 * 256;
  ushort* lplane = hplane + 256 * 256;
  hplane[n * 256 + k] = h;
  lplane[n * 256 + k] = l;
}

// ---------------- bf16 MFMA GEMM with f32-precision W (hi+lo planes) ----------
// XW[M,256] bf16 = round_bf16( A[M,256] @ (Wh+Wl) ), A bf16, acc f32.
// BM=64, BN=256 (full width), BK=32, 256 threads = 4 waves.
// Wave w computes all 64 rows x cols [w*64, w*64+64): acc[4][4].
// 2-phase double-buffered pipeline: stage k-step t+1 before computing t.
// LDS kblk-major slots (16B): A slot = kb*64+row, B slot = kb*256+row ->
// 16-lane fragment groups read consecutive slots (2-way bank alias = free).
#define GBM 64
#define GBK 32

__device__ __forceinline__ void gload16(const void* g, void* l) {
  __builtin_amdgcn_global_load_lds(
      (const __attribute__((address_space(1))) void*)g,
      (__attribute__((address_space(3))) void*)l, 16, 0, 0);
}

__global__ __launch_bounds__(256) void gemm_mfma(
    const ushort* __restrict__ A,                                  // [N_PAD][256] bf16
    const ushort* __restrict__ Wh, const ushort* __restrict__ Wl,  // [256][256] n-major
    ushort* __restrict__ C, int M) {
  __shared__ ushort Asl[2][GBM * GBK];   // 2 x 4KB
  __shared__ ushort Bhs[2][256 * GBK];   // 2 x 16KB
  __shared__ ushort Bls[2][256 * GBK];   // 2 x 16KB
  int tid = threadIdx.x;
  int bm = blockIdx.x * GBM;
  int wave = tid >> 6, lane = tid & 63;
  int wc = wave * 64;
  int l15 = lane & 15;
  int lkb = lane >> 4;

  f32x4 acc[4][4];
#pragma unroll
  for (int i = 0; i < 4; ++i)
#pragma unroll
    for (int j = 0; j < 4; ++j) acc[i][j] = (f32x4){0.f, 0.f, 0.f, 0.f};

  int arow = tid & 63, akb = tid >> 6;   // A: 256 slots, 1 per thread

#define STAGE(buf, k0)                                                         \
  do {                                                                         \
    gload16(A + (size_t)(bm + arow) * 256 + (k0) + akb * 8,                    \
            &Asl[buf][tid * 8]);                                               \
    _Pragma("unroll") for (int it = 0; it < 4; ++it) {                         \
      gload16(Wh + (size_t)tid * 256 + (k0) + it * 8,                          \
              &Bhs[buf][(it * 256 + tid) * 8]);                                \
      gload16(Wl + (size_t)tid * 256 + (k0) + it * 8,                          \
              &Bls[buf][(it * 256 + tid) * 8]);                                \
    }                                                                          \
  } while (0)

  STAGE(0, 0);
  __syncthreads();
  int cur = 0;
  for (int t = 0; t < 8; ++t) {
    if (t < 7) STAGE(cur ^ 1, (t + 1) * GBK);   // prefetch next k-step
    s16x8 af[4], bh[4], bl[4];
#pragma unroll
    for (int f = 0; f < 4; ++f) {
      af[f] = *(const s16x8*)(&Asl[cur][(lkb * 64 + f * 16 + l15) * 8]);
      bh[f] = *(const s16x8*)(&Bhs[cur][(lkb * 256 + wc + f * 16 + l15) * 8]);
      bl[f] = *(const s16x8*)(&Bls[cur][(lkb * 256 + wc + f * 16 + l15) * 8]);
    }
#pragma unroll
    for (int i = 0; i < 4; ++i)
#pragma unroll
      for (int j = 0; j < 4; ++j) {
        acc[i][j] = __builtin_amdgcn_mfma_f32_16x16x32_bf16(af[i], bh[j], acc[i][j], 0, 0, 0);
        acc[i][j] = __builtin_amdgcn_mfma_f32_16x16x32_bf16(af[i], bl[j], acc[i][j], 0, 0, 0);
      }
    __syncthreads();   // drains prefetch; next iter reads cur^1 safely
    cur ^= 1;
  }
#undef STAGE

#pragma unroll
  for (int i = 0; i < 4; ++i) {
    int rbase = bm + i * 16 + (lane >> 4) * 4;
#pragma unroll
    for (int j = 0; j < 4; ++j) {
      int col = wc + j * 16 + l15;
#pragma unroll
      for (int r = 0; r < 4; ++r) {
        int row = rbase + r;
        if (row < M) C[(size_t)row * 256 + col] = bf16_hi(acc[i][j][r]);
      }
    }
  }
}

// ---------------- SpMM: bf16 gather table, 1 wave/node, 8-edge unroll ----------------
// MODE 0: write bf16 x (feeds next layer's GEMM A)
// MODE 1: write f32 x (feeds pooling)
template <int MODE>
__global__ __launch_bounds__(256) void spmm4(
    const ushort* __restrict__ xw, const int* __restrict__ rs,
    const int* __restrict__ csrc, const float* __restrict__ cw,
    const float* __restrict__ dinv, const float* __restrict__ bias,
    float* __restrict__ xf32, ushort* __restrict__ xhi) {
  int wave = threadIdx.x >> 6, lane = threadIdx.x & 63;
  int n = blockIdx.x * 4 + wave;  // 50000 = 12500*4 exact
  float di = dinv[n];
  const ushort4* base = (const ushort4*)xw;
  size_t rowoff = (size_t)n * 64 + lane;
  ushort4 selfh = base[rowoff];
  float dd = di * di;
  float ax = bf16_up(selfh.x) * dd, ay = bf16_up(selfh.y) * dd;
  float az = bf16_up(selfh.z) * dd, aw = bf16_up(selfh.w) * dd;
  int s = rs[n], e = rs[n + 1];
  int i = s;
  for (; i + 8 <= e; i += 8) {
    int idx[8];
    float w[8];
    ushort4 v[8];
#pragma unroll
    for (int u = 0; u < 8; ++u) { idx[u] = csrc[i + u]; w[u] = cw[i + u]; }
#pragma unroll
    for (int u = 0; u < 8; ++u) v[u] = base[(size_t)idx[u] * 64 + lane];
#pragma unroll
    for (int u = 0; u < 8; ++u) {
      ax += w[u] * bf16_up(v[u].x);
      ay += w[u] * bf16_up(v[u].y);
      az += w[u] * bf16_up(v[u].z);
      aw += w[u] * bf16_up(v[u].w);
    }
  }
  for (; i + 4 <= e; i += 4) {
    int idx[4];
    float w[4];
    ushort4 v[4];
#pragma unroll
    for (int u = 0; u < 4; ++u) { idx[u] = csrc[i + u]; w[u] = cw[i + u]; }
#pragma unroll
    for (int u = 0; u < 4; ++u) v[u] = base[(size_t)idx[u] * 64 + lane];
#pragma unroll
    for (int u = 0; u < 4; ++u) {
      ax += w[u] * bf16_up(v[u].x);
      ay += w[u] * bf16_up(v[u].y);
      az += w[u] * bf16_up(v[u].z);
      aw += w[u] * bf16_up(v[u].w);
    }
  }
  for (; i < e; ++i) {
    float w0 = cw[i];
    ushort4 v0 = base[(size_t)csrc[i] * 64 + lane];
    ax += w0 * bf16_up(v0.x);
    ay += w0 * bf16_up(v0.y);
    az += w0 * bf16_up(v0.z);
    aw += w0 * bf16_up(v0.w);
  }
  float4 b = ((const float4*)bias)[lane];
  ax = fmaxf(ax + b.x, 0.f);
  ay = fmaxf(ay + b.y, 0.f);
  az = fmaxf(az + b.z, 0.f);
  aw = fmaxf(aw + b.w, 0.f);
  if (MODE == 1) {
    float4 r;
    r.x = ax; r.y = ay; r.z = az; r.w = aw;
    ((float4*)xf32)[rowoff] = r;
  } else {
    ushort4 h;
    h.x = bf16_hi(ax);
    h.y = bf16_hi(ay);
    h.z = bf16_hi(az);
    h.w = bf16_hi(aw);
    ((ushort4*)xhi)[rowoff] = h;
  }
}

// ---------------- pooling: grid (graph, dim-chunk), 4 node-lanes ----------------
__device__ __forceinline__ int lower_bound_dev(const int* a, int n, int key) {
  int lo = 0, hi = n;
  while (lo < hi) {
    int mid = (lo + hi) >> 1;
    if (a[mid] < key) lo = mid + 1; else hi = mid;
  }
  return lo;
}

__global__ __launch_bounds__(256) void pool_kernel(
    const float* __restrict__ x, const int* __restrict__ batch,
    float* __restrict__ h) {
  int g = blockIdx.x;
  int dchunk = blockIdx.y;
  int t = threadIdx.x;
  int dl = t & 63;
  int nl = t >> 6;
  int d = dchunk * 64 + dl;
  int start = lower_bound_dev(batch, N_NODES, g);
  int end = lower_bound_dev(batch, N_NODES, g + 1);
  float sum = 0.f, mx = 0.f;
  for (int i = start + nl; i < end; i += 4) {
    float v = x[(size_t)i * DIM + d];
    sum += v;
    mx = fmaxf(mx, v);
  }
  __shared__ float ssum[4][64];
  __shared__ float smax[4][64];
  ssum[nl][dl] = sum;
  smax[nl][dl] = mx;
  __syncthreads();
  if (nl == 0) {
    sum = ssum[0][dl] + ssum[1][dl] + ssum[2][dl] + ssum[3][dl];
    mx = fmaxf(fmaxf(smax[0][dl], smax[1][dl]), fmaxf(smax[2][dl], smax[3][dl]));
    float cnt = (float)(end - start);
    h[(size_t)g * (2 * DIM) + d] = sum / fmaxf(cnt, 1.0f);
    h[(size_t)g * (2 * DIM) + DIM + d] = mx;
  }
}

// ---------------- FC head ----------------
__global__ __launch_bounds__(256) void fc_kernel(
    const float* __restrict__ h, const float* __restrict__ fc1_w,
    const float* __restrict__ fc1_b, const float* __restrict__ fc2_w,
    const float* __restrict__ fc2_b, float* __restrict__ out) {
  int g = blockIdx.x;
  int j = threadIdx.x;
  __shared__ float hs[2 * DIM];
  __shared__ float s0[256], s1[256];
  hs[j] = h[(size_t)g * (2 * DIM) + j];
  hs[j + 256] = h[(size_t)g * (2 * DIM) + 256 + j];
  __syncthreads();
  float acc = fc1_b[j];
  for (int k = 0; k < 2 * DIM; ++k) acc += hs[k] * fc1_w[(size_t)k * DIM + j];
  float r = fmaxf(acc, 0.0f);
  s0[j] = r * fc2_w[j * 2 + 0];
  s1[j] = r * fc2_w[j * 2 + 1];
  __syncthreads();
  for (int off = 128; off > 0; off >>= 1) {
    if (j < off) { s0[j] += s0[j + off]; s1[j] += s1[j + off]; }
    __syncthreads();
  }
  if (j == 0) {
    out[g * 2 + 0] = s0[0] + fc2_b[0];
    out[g * 2 + 1] = s1[0] + fc2_b[1];
  }
}

extern "C" void kernel_launch(void* const* d_in, const int* in_sizes, int n_in,
                              void* d_out, int out_size, void* d_ws, size_t ws_size,
                              hipStream_t stream) {
  const float* emb_x = (const float*)d_in[0];
  const int* eidx = (const int*)d_in[1];
  const int* esrc = eidx;
  const int* edst = eidx + N_EDGES;
  const float* ew = (const float*)d_in[2];
  const int* batch = (const int*)d_in[3];
  const float* W1 = (const float*)d_in[4];
  const float* b1 = (const float*)d_in[5];
  const float* W2 = (const float*)d_in[6];
  const float* b2 = (const float*)d_in[7];
  const float* W3 = (const float*)d_in[8];
  const float* b3 = (const float*)d_in[9];
  const float* fc1_w = (const float*)d_in[10];
  const float* fc1_b = (const float*)d_in[11];
  const float* fc2_w = (const float*)d_in[12];
  const float* fc2_b = (const float*)d_in[13];
  float* out = (float*)d_out;

  char* ws = (char*)d_ws;
  size_t off = 0;
  auto take = [&](size_t bytes) -> char* {
    char* p = ws + off;
    off = (off + bytes + 255) & ~(size_t)255;
    return p;
  };
  ushort* XW = (ushort*)take((size_t)N_PAD * DIM * 2);    // bf16 gather table
  ushort* Xhi = (ushort*)take((size_t)N_PAD * DIM * 2);   // bf16 x (GEMM A)
  float* Xf32 = (float*)take((size_t)N_NODES * DIM * 4);  // layer-3 f32 out for pooling
  ushort* WT = (ushort*)take((size_t)6 * 256 * 256 * 2);
  float* deg = (float*)take(N_NODES * 4);
  float* dinv = (float*)take(N_NODES * 4);
  int* counts = (int*)take(N_NODES * 4);
  int* rs = (int*)take((N_NODES + 1) * 4);
  int* cursor = (int*)take(N_NODES * 4);
  int* blockSums = (int*)take(64 * 4);
  int* csrc = (int*)take(N_EDGES * 4);
  float* cw = (float*)take(N_EDGES * 4);
  float* h = (float*)take((size_t)N_GRAPHS * 2 * DIM * 4);

  hipMemsetAsync(deg, 0, N_NODES * 4, stream);
  hipMemsetAsync(counts, 0, N_NODES * 4, stream);
  // zero padded tail rows of Xhi (read by gemm as A rows >= N_NODES)
  hipMemsetAsync(Xhi + (size_t)N_NODES * DIM, 0, (size_t)(N_PAD - N_NODES) * DIM * 2, stream);

  int eblocks = (N_EDGES + 255) / 256;
  int nblocks = (N_NODES + 255) / 256;

  deg_count_kernel<<<eblocks, 256, 0, stream>>>(edst, ew, deg, counts);
  dinv_kernel<<<nblocks, 256, 0, stream>>>(deg, dinv);
  scan_phaseA<<<SCAN_BLOCKS, 256, 0, stream>>>(counts, blockSums);
  scan_phaseB<<<1, 64, 0, stream>>>(blockSums, rs);
  scan_phaseC<<<SCAN_BLOCKS, 256, 0, stream>>>(counts, blockSums, rs, cursor);
  fill_kernel<<<eblocks, 256, 0, stream>>>(esrc, edst, ew, dinv, cursor, csrc, cw);

  round_x_kernel<<<(N_NODES * DIM / 4 + 255) / 256, 256, 0, stream>>>(
      emb_x, Xhi, N_NODES * DIM / 4);
  prep_w_kernel<<<dim3(256, 3), 256, 0, stream>>>(W1, W2, W3, WT);

  ushort* W1h = WT + 0 * 65536; ushort* W1l = WT + 1 * 65536;
  ushort* W2h = WT + 2 * 65536; ushort* W2l = WT + 3 * 65536;
  ushort* W3h = WT + 4 * 65536; ushort* W3l = WT + 5 * 65536;

  dim3 ggrid(N_PAD / GBM);  // 782 blocks

  // layer 1
  gemm_mfma<<<ggrid, 256, 0, stream>>>(Xhi, W1h, W1l, XW, N_NODES);
  spmm4<0><<<N_NODES / 4, 256, 0, stream>>>(XW, rs, csrc, cw, dinv, b1, nullptr, Xhi);
  // layer 2
  gemm_mfma<<<ggrid, 256, 0, stream>>>(Xhi, W2h, W2l, XW, N_NODES);
  spmm4<0><<<N_NODES / 4, 256, 0, stream>>>(XW, rs, csrc, cw, dinv, b2, nullptr, Xhi);
  // layer 3
  gemm_mfma<<<ggrid, 256, 0, stream>>>(Xhi, W3h, W3l, XW, N_NODES);
  spmm4<1><<<N_NODES / 4, 256, 0, stream>>>(XW, rs, csrc, cw, dinv, b3, Xf32, nullptr);

  pool_kernel<<<dim3(N_GRAPHS, 4), 256, 0, stream>>>(Xf32, batch, h);
  fc_kernel<<<N_GRAPHS, 256, 0, stream>>>(h, fc1_w, fc1_b, fc2_w, fc2_b, out);
}